// Round 14
// baseline (810.790 us; speedup 1.0000x reference)
//
#include <hip/hip_runtime.h>
#include <math.h>

// ---------- problem constants ----------
constexpr int SEQ_T = 72;
constexpr int FDIM  = 64;
constexpr int UNITS = 256;
constexpr int U4    = 1024;
constexpr int BATCH = 4096;
constexpr int NKC   = 10;          // k-chunks of 32 (x: kc0-1, h: kc2-9)
constexpr float LOG2E = 1.4426950408889634f;

// Partition: 256 blocks = 64 row-groups (64 rows) x 4 unit-quarters (64 units x 4 gates).
// blk = rg + ub*64 -> group shares blk%8 (same XCD, perf-only heuristic).
// Weights per block: 160 KB -> 96 KB LDS (kc0-5) + 64 VGPR/lane (kc6-9).
// h exchanged via L3 (agent-scope relaxed); per-group 4-block barrier.
// Own h-quarter bypasses the exchange (written straight into A_s).

// LDS (dynamic, shorts):
constexpr int A_SH    = NKC * 4 * 64 * 8;        // 20480 sh = 40960 B   [kc][m4][64][8]
constexpr int WL_SH   = 6 * 4 * 4 * 64 * 8;      // 49152 sh = 98304 B   [kc<6][ug][g][64][8]
constexpr int HST_SH  = 2 * 4 * 64 * 8;          // 4096 sh  = 8192 B    [kcq][m4][64][8]
constexpr int LDS_BYTES = (A_SH + WL_SH + HST_SH) * 2;   // 147456

using bf16x8 = __attribute__((ext_vector_type(8))) short;
using bf16x4 = __attribute__((ext_vector_type(4))) short;
using f32x4  = __attribute__((ext_vector_type(4))) float;
using ull    = unsigned long long;

// z pre-scaled by log2e: sigmoid(z) = 1/(1+2^-z')
__device__ __forceinline__ float sig2(float x) {
    return __builtin_amdgcn_rcpf(1.0f + exp2f(-x));
}
// tanh(z) with z' = z*log2e: 1 - 2/(2^(2|z'|)+1)
__device__ __forceinline__ float tanh2(float x) {
    float t = 1.0f - 2.0f * __builtin_amdgcn_rcpf(exp2f(2.0f * fabsf(x)) + 1.0f);
    return copysignf(t, x);
}
// tanh of an UNscaled value (cell state)
__device__ __forceinline__ float tanhc(float x) {
    float t = 1.0f - 2.0f * __builtin_amdgcn_rcpf(exp2f(2.0f * LOG2E * fabsf(x)) + 1.0f);
    return copysignf(t, x);
}
__device__ __forceinline__ unsigned short f2bf(float f) {
    union { float f; unsigned u; } v; v.f = f;
    unsigned r = (v.u + 0x7FFFu + ((v.u >> 16) & 1u)) >> 16;   // RNE
    return (unsigned short)r;
}

// ---------- prep: z-weights (PRE-SCALED by log2e), blob idx = (((ub*10+kc)*4+ug)*4+g)*64+l ----------
// col = g*256 + ub*64 + ug*16 + (l&15) ; k = kc*32 + (l>>4)*8 + e
__global__ void prep_wblob(const float* __restrict__ W, const float* __restrict__ U,
                           unsigned short* __restrict__ Wblob) {
    int id = blockIdx.x * 256 + threadIdx.x;    // 40960
    int l    = id & 63;
    int g    = (id >> 6) & 3;
    int ug   = (id >> 8) & 3;
    int rest = id >> 10;                         // ub*10 + kc
    int kc   = rest % 10, ub = rest / 10;
    int col  = g * 256 + ub * 64 + ug * 16 + (l & 15);
    int kb   = kc * 32 + (l >> 4) * 8;
    bf16x8 v;
    #pragma unroll
    for (int e = 0; e < 8; ++e) {
        int k = kb + e;
        float f = (k < FDIM) ? W[(size_t)k * U4 + col] : U[(size_t)(k - FDIM) * U4 + col];
        v[e] = (short)f2bf(f * LOG2E);
    }
    *reinterpret_cast<bf16x8*>(Wblob + (size_t)id * 8) = v;
}

// ---------- prep: dense weights (unscaled), blob idx = (ft*8 + kcd)*64 + l ----------
__global__ void prep_wdblob(const float* __restrict__ Wd, unsigned short* __restrict__ Wdblob) {
    int id = blockIdx.x * 256 + threadIdx.x;    // 2048
    int l   = id & 63;
    int kcd = (id >> 6) & 7;
    int ft  = id >> 9;
    int f   = ft * 16 + (l & 15);
    int kb  = kcd * 32 + (l >> 4) * 8;
    bf16x8 v;
    #pragma unroll
    for (int e = 0; e < 8; ++e)
        v[e] = (short)f2bf(Wd[(size_t)(kb + e) * FDIM + f]);
    *reinterpret_cast<bf16x8*>(Wdblob + (size_t)id * 8) = v;
}

// AGENT-scope relaxed 8B ops: bypass per-XCD L2, coherence point = L3.
__device__ __forceinline__ ull agload(const ull* p) {
    return __hip_atomic_load(p, __ATOMIC_RELAXED, __HIP_MEMORY_SCOPE_AGENT);
}
__device__ __forceinline__ void agstore(ull* p, ull v) {
    __hip_atomic_store(p, v, __ATOMIC_RELAXED, __HIP_MEMORY_SCOPE_AGENT);
}

// ---------- persistent unit-split LSTM, 16 waves ----------
// grid 256 x 1024. rg = blk&63, ub = blk>>6. Block: rows [rg*64,+64), units
// [ub*64,+64) x 4 gates. Wave w: ug = w&3 (16 units), m4 = w>>2 (16-row tile).
__global__ __launch_bounds__(1024) void lstm_persistent(
    const float* __restrict__ inputs,          // [B][72][64] fp32
    const float* __restrict__ bias,            // [1024] fp32
    const unsigned short* __restrict__ Wblob,  // z-weight blobs (640 KB, pre-scaled)
    const unsigned short* __restrict__ Wdblob, // dense blobs (32 KB)
    const float* __restrict__ bd,              // [64] fp32
    unsigned short* __restrict__ hbuf,         // [2][64 rg][8 kc][4 m][64][8] bf16
    unsigned int* __restrict__ barcnt,         // [64 groups x 32] (128B-spaced)
    float* __restrict__ out,                   // [B][out_steps][64] fp32
    int out_steps)
{
    extern __shared__ char smem[];
    unsigned short* A_s = (unsigned short*)smem;                       // [10][4][64][8]
    unsigned short* WL  = (unsigned short*)(smem + A_SH * 2);          // [6][4][4][64][8]
    unsigned short* hst = (unsigned short*)(smem + (A_SH + WL_SH) * 2);// [2][4][64][8]

    const int tid  = threadIdx.x;
    const int w    = tid >> 6, lane = tid & 63;
    const int l16  = lane & 15, hi4 = lane >> 4;
    const int blk  = blockIdx.x;
    const int rg   = blk & 63, ub = blk >> 6;
    const int bb   = rg * 64;
    const int ug   = w & 3;                    // 16-unit group within block
    const int m4   = w >> 2;                   // 16-row tile

    // ---- LDS weights kc0-5: contiguous 96 KB (once) ----
    {
        const unsigned short* src = Wblob + (size_t)(ub * 10) * 16 * 512;
        #pragma unroll
        for (int i = 0; i < 6; ++i) {
            int idx = (i * 1024 + tid) * 8;
            *reinterpret_cast<bf16x8*>(WL + idx) =
                *reinterpret_cast<const bf16x8*>(src + idx);
        }
    }
    // ---- register weights kc6-9 (wave's ug slice): 64 VGPRs ----
    bf16x8 Breg[4][4];
    #pragma unroll
    for (int i = 0; i < 4; ++i)
        #pragma unroll
        for (int g = 0; g < 4; ++g)
            Breg[i][g] = *reinterpret_cast<const bf16x8*>(
                Wblob + ((size_t)(((ub * 10 + 6 + i) * 4 + ug) * 4 + g) * 64 + lane) * 8);

    const int uu = ub * 64 + ug * 16 + l16;
    float bz[4];
    #pragma unroll
    for (int g = 0; g < 4; ++g) bz[g] = bias[g * 256 + uu] * LOG2E;
    const float bdv = bd[(w & 3) * 16 + l16];

    float c_reg[4] = {0.f, 0.f, 0.f, 0.f};

    // epilogue h-placement constants (own quarter)
    const int kcq  = ug >> 1;                              // quarter-relative kc
    const int lb   = (ug & 1) * 2 + (l16 >> 3);            // k-subgroup within blob lane
    const int elem = l16 & 7;

    const int tmax = SEQ_T + out_steps - 1;    // 95
    const size_t HB = (size_t)64 * 16384;      // hbuf parity stride (shorts)

    #pragma unroll 1
    for (int t = 0; ; ++t) {
        const int p = t & 1;

        // ---- stage h_t: 3 REMOTE quarters (own written by t-1 epilogue) ----
        if (t == 0) {
            #pragma unroll
            for (int i = 0; i < 4; ++i)
                *reinterpret_cast<ull*>(A_s + 4096 + (i * 1024 + tid) * 4) = 0ull;
        } else {
            const ull* src = reinterpret_cast<const ull*>(hbuf + p * HB + (size_t)rg * 16384);
            ull vbuf[4];
            bool use[4];
            #pragma unroll
            for (int ii = 0; ii < 4; ++ii) {
                int lin = ii * 1024 + tid;
                use[ii] = ((lin >> 10) != ub);             // quarter = (lin>>9)>>1
                if (use[ii]) vbuf[ii] = agload(src + lin);
            }
            #pragma unroll
            for (int ii = 0; ii < 4; ++ii)
                if (use[ii])
                    *reinterpret_cast<ull*>(A_s + 4096 + (ii * 1024 + tid) * 4) = vbuf[ii];
        }

        if (t < SEQ_T) {
            // ---- stage x(t): float4/thread -> A kc0,1 ----
            int r = tid >> 4, c4 = (tid & 15) * 4;
            float4 v = *reinterpret_cast<const float4*>(
                inputs + ((size_t)(bb + r) * SEQ_T + t) * FDIM + c4);
            bf16x4 pk;
            pk[0] = (short)f2bf(v.x); pk[1] = (short)f2bf(v.y);
            pk[2] = (short)f2bf(v.z); pk[3] = (short)f2bf(v.w);
            int kcx = c4 >> 5;
            int lnb = (r & 15) | ((((c4 & 31) >> 3)) << 4);
            *reinterpret_cast<bf16x4*>(
                A_s + ((kcx * 4 + (r >> 4)) * 64 + lnb) * 8 + (c4 & 7)) = pk;
            __syncthreads();                   // A ready
        } else {
            __syncthreads();                   // remote h staged
            // ---- dense head: wave (ft=w&3, m4) tile ----
            const int s = t - SEQ_T;
            const int f = (w & 3) * 16 + l16;
            f32x4 accp = {0.f, 0.f, 0.f, 0.f};
            #pragma unroll
            for (int kcd = 0; kcd < 8; ++kcd) {
                bf16x8 a = *reinterpret_cast<const bf16x8*>(
                    A_s + (((2 + kcd) * 4 + m4) * 64 + lane) * 8);
                bf16x8 bw = *reinterpret_cast<const bf16x8*>(
                    Wdblob + (size_t)((((w & 3) * 8 + kcd) * 64) + lane) * 8);
                accp = __builtin_amdgcn_mfma_f32_16x16x32_bf16(a, bw, accp, 0, 0, 0);
            }
            const int kcx = f >> 5;
            const int lshf = (((f & 31) >> 3)) << 4;
            #pragma unroll
            for (int j = 0; j < 4; ++j) {
                int row = m4 * 16 + hi4 * 4 + j;
                float v = accp[j] + bdv;
                if (ub == 0)
                    out[((size_t)(bb + row) * out_steps + s) * FDIM + f] = v;
                A_s[((kcx * 4 + m4) * 64 + ((row & 15) | lshf)) * 8 + (f & 7)] = f2bf(v);
            }
            if (t == tmax) break;
            __syncthreads();                   // feedback x staged
        }

        // ================ z = [x|h] @ Wslice (weights resident) ================
        f32x4 acc[4];
        #pragma unroll
        for (int g = 0; g < 4; ++g) acc[g] = (f32x4){0.f, 0.f, 0.f, 0.f};

        #pragma unroll
        for (int kc = 0; kc < NKC; ++kc) {
            bf16x8 a = *reinterpret_cast<const bf16x8*>(
                A_s + ((kc * 4 + m4) * 64 + lane) * 8);
            #pragma unroll
            for (int g = 0; g < 4; ++g) {
                bf16x8 bw = (kc < 6)
                    ? *reinterpret_cast<const bf16x8*>(
                          WL + (((kc * 4 + ug) * 4 + g) * 64 + lane) * 8)
                    : Breg[kc - 6][g];
                acc[g] = __builtin_amdgcn_mfma_f32_16x16x32_bf16(a, bw, acc[g], 0, 0, 0);
            }
        }
        __syncthreads();                       // all z reads of A done

        // ================ gates; h -> hst (publish) + A_s own quarter ================
        #pragma unroll
        for (int j = 0; j < 4; ++j) {
            float zi = acc[0][j] + bz[0];
            float zf = acc[1][j] + bz[1];
            float zg = acc[2][j] + bz[2];
            float zo = acc[3][j] + bz[3];
            float ig = sig2(zi);
            float fg = sig2(zf);
            float og = sig2(zo);
            float cn = fg * c_reg[j] + ig * tanh2(zg);
            c_reg[j] = cn;
            unsigned short hv = f2bf(og * tanhc(cn));
            int rl = hi4 * 4 + j;
            int lnb = rl | (lb << 4);
            hst[((kcq * 4 + m4) * 64 + lnb) * 8 + elem] = hv;
            A_s[(((2 + 2 * ub + kcq) * 4 + m4) * 64 + lnb) * 8 + elem] = hv;
        }
        __syncthreads();                       // hst complete

        // ---- publish own quarter (8 KB) to hbuf[1-p] ----
        {
            ull* dst = reinterpret_cast<ull*>(
                hbuf + (1 - p) * HB + (size_t)rg * 16384 + (size_t)ub * 4096);
            agstore(dst + tid, reinterpret_cast<const ull*>(hst)[tid]);
        }
        __syncthreads();                       // drains vmcnt: stores at L3

        // ---- per-group barrier (4 blocks) ----
        if (tid == 0) {
            unsigned int* cnt = barcnt + rg * 32;
            __hip_atomic_fetch_add(cnt, 1u, __ATOMIC_RELAXED, __HIP_MEMORY_SCOPE_AGENT);
            const unsigned target = 4u * (unsigned)(t + 1);
            while (__hip_atomic_load(cnt, __ATOMIC_RELAXED, __HIP_MEMORY_SCOPE_AGENT) < target)
                __builtin_amdgcn_s_sleep(2);
        }
        __syncthreads();                       // release
    }
}

extern "C" void kernel_launch(void* const* d_in, const int* in_sizes, int n_in,
                              void* d_out, int out_size, void* d_ws, size_t ws_size,
                              hipStream_t stream) {
    const float* inputs = (const float*)d_in[0];
    const float* W      = (const float*)d_in[1];
    const float* U      = (const float*)d_in[2];
    const float* b      = (const float*)d_in[3];
    const float* Wd     = (const float*)d_in[4];
    const float* bd     = (const float*)d_in[5];
    float* out = (float*)d_out;

    const int out_steps = out_size / (BATCH * FDIM);   // 24

    char* ws = (char*)d_ws;
    unsigned short* Wblob  = (unsigned short*)(ws);               // 640 KB
    unsigned short* Wdblob = (unsigned short*)(ws + (1u << 20));  // 32 KB
    unsigned short* hbuf   = (unsigned short*)(ws + (2u << 20));  // 4 MB
    unsigned int*   barcnt = (unsigned int*)(ws + (6u << 20));    // 64 x 128 B

    prep_wblob<<<160, 256, 0, stream>>>(W, U, Wblob);
    prep_wdblob<<<8, 256, 0, stream>>>(Wd, Wdblob);
    hipMemsetAsync(barcnt, 0, 64 * 128, stream);

    (void)hipFuncSetAttribute((const void*)lstm_persistent,
                              hipFuncAttributeMaxDynamicSharedMemorySize, LDS_BYTES);

    lstm_persistent<<<dim3(256), dim3(1024), LDS_BYTES, stream>>>(
        inputs, b, Wblob, Wdblob, bd, hbuf, barcnt, out, out_steps);
}

// Round 15
// 481.590 us; speedup vs baseline: 1.6836x; 1.6836x over previous
//
#include <hip/hip_runtime.h>
#include <math.h>

// ---------- problem constants ----------
constexpr int SEQ_T = 72;
constexpr int FDIM  = 64;
constexpr int UNITS = 256;
constexpr int U4    = 1024;
constexpr int BATCH = 4096;
constexpr int NKC   = 10;          // k-chunks of 32 (x: kc0-1, h: kc2-9)
constexpr float LOG2E = 1.4426950408889634f;

// Partition: 256 blocks = 64 row-groups (64 rows) x 4 unit-quarters (64 units x 4 gates).
// blk = rg + ub*64 -> group shares blk%8 (same XCD, perf-only heuristic).
// Weights per block: 160 KB -> 96 KB LDS (kc0-5) + 64 VGPR/lane (kc6-9).
// h exchanged via L3 (agent-scope relaxed); per-group flag barrier (no RMW).

// LDS (dynamic, shorts):
constexpr int A_SH    = NKC * 4 * 64 * 8;        // 20480 sh = 40960 B   [kc][m4][64][8]
constexpr int WL_SH   = 6 * 4 * 4 * 64 * 8;      // 49152 sh = 98304 B   [kc<6][ug][g][64][8]
constexpr int HST_SH  = 2 * 4 * 64 * 8;          // 4096 sh  = 8192 B    [kcb][m4][64][8]
constexpr int LDS_BYTES = (A_SH + WL_SH + HST_SH) * 2;   // 147456

using bf16x8 = __attribute__((ext_vector_type(8))) short;
using f32x4  = __attribute__((ext_vector_type(4))) float;
using ull    = unsigned long long;

// z pre-scaled by log2e: sigmoid(z) = 1/(1+2^-z')
__device__ __forceinline__ float sig2(float x) {
    return __builtin_amdgcn_rcpf(1.0f + exp2f(-x));
}
// tanh(z) from z' = z*log2e
__device__ __forceinline__ float tanh2(float x) {
    float t = 1.0f - 2.0f * __builtin_amdgcn_rcpf(exp2f(2.0f * fabsf(x)) + 1.0f);
    return copysignf(t, x);
}
// tanh of an UNscaled value (cell state)
__device__ __forceinline__ float tanhc(float x) {
    float t = 1.0f - 2.0f * __builtin_amdgcn_rcpf(exp2f(2.0f * LOG2E * fabsf(x)) + 1.0f);
    return copysignf(t, x);
}
__device__ __forceinline__ unsigned short f2bf(float f) {
    union { float f; unsigned u; } v; v.f = f;
    unsigned r = (v.u + 0x7FFFu + ((v.u >> 16) & 1u)) >> 16;   // RNE
    return (unsigned short)r;
}
__device__ __forceinline__ bf16x8 pack8(float4 a, float4 b) {
    bf16x8 p;
    p[0] = (short)f2bf(a.x); p[1] = (short)f2bf(a.y);
    p[2] = (short)f2bf(a.z); p[3] = (short)f2bf(a.w);
    p[4] = (short)f2bf(b.x); p[5] = (short)f2bf(b.y);
    p[6] = (short)f2bf(b.z); p[7] = (short)f2bf(b.w);
    return p;
}

// ---------- prep: z-weights (PRE-SCALED by log2e), blob idx = (((ub*10+kc)*4+ug)*4+g)*64+l ----------
// col = g*256 + ub*64 + ug*16 + (l&15) ; k = kc*32 + (l>>4)*8 + e
__global__ void prep_wblob(const float* __restrict__ W, const float* __restrict__ U,
                           unsigned short* __restrict__ Wblob) {
    int id = blockIdx.x * 256 + threadIdx.x;    // 40960
    int l    = id & 63;
    int g    = (id >> 6) & 3;
    int ug   = (id >> 8) & 3;
    int rest = id >> 10;                         // ub*10 + kc
    int kc   = rest % 10, ub = rest / 10;
    int col  = g * 256 + ub * 64 + ug * 16 + (l & 15);
    int kb   = kc * 32 + (l >> 4) * 8;
    bf16x8 v;
    #pragma unroll
    for (int e = 0; e < 8; ++e) {
        int k = kb + e;
        float f = (k < FDIM) ? W[(size_t)k * U4 + col] : U[(size_t)(k - FDIM) * U4 + col];
        v[e] = (short)f2bf(f * LOG2E);
    }
    *reinterpret_cast<bf16x8*>(Wblob + (size_t)id * 8) = v;
}

// ---------- prep: dense weights (unscaled), blob idx = (ft*8 + kcd)*64 + l ----------
__global__ void prep_wdblob(const float* __restrict__ Wd, unsigned short* __restrict__ Wdblob) {
    int id = blockIdx.x * 256 + threadIdx.x;    // 2048
    int l   = id & 63;
    int kcd = (id >> 6) & 7;
    int ft  = id >> 9;
    int f   = ft * 16 + (l & 15);
    int kb  = kcd * 32 + (l >> 4) * 8;
    bf16x8 v;
    #pragma unroll
    for (int e = 0; e < 8; ++e)
        v[e] = (short)f2bf(Wd[(size_t)(kb + e) * FDIM + f]);
    *reinterpret_cast<bf16x8*>(Wdblob + (size_t)id * 8) = v;
}

// AGENT-scope relaxed ops: bypass per-XCD L2, coherence point = L3.
__device__ __forceinline__ ull agload(const ull* p) {
    return __hip_atomic_load(p, __ATOMIC_RELAXED, __HIP_MEMORY_SCOPE_AGENT);
}
__device__ __forceinline__ void agstore(ull* p, ull v) {
    __hip_atomic_store(p, v, __ATOMIC_RELAXED, __HIP_MEMORY_SCOPE_AGENT);
}

// ---------- persistent unit-split LSTM: weights CU-resident ----------
// grid 256 x 512 (8 waves). rg = blk & 63, ub = blk >> 6. Block owns rows
// [rg*64,+64), units [ub*64,+64) x 4 gates. Wave w: ug = w&3, row-half = w>>2.
__global__ __launch_bounds__(512, 1) void lstm_persistent(
    const float* __restrict__ inputs,          // [B][72][64] fp32
    const float* __restrict__ bias,            // [1024] fp32
    const unsigned short* __restrict__ Wblob,  // z-weight blobs (640 KB, pre-scaled)
    const unsigned short* __restrict__ Wdblob, // dense blobs (32 KB)
    const float* __restrict__ bd,              // [64] fp32
    unsigned short* __restrict__ hbuf,         // [2][64 rg][8 kc][4 m][64][8] bf16
    unsigned int* __restrict__ flags,          // [64 groups x 32] (128B-spaced)
    float* __restrict__ out,                   // [B][out_steps][64] fp32
    int out_steps)
{
    extern __shared__ char smem[];
    unsigned short* A_s = (unsigned short*)smem;                       // [10][4][64][8]
    unsigned short* WL  = (unsigned short*)(smem + A_SH * 2);          // [6][4][4][64][8]
    unsigned short* hst = (unsigned short*)(smem + (A_SH + WL_SH) * 2);// [2][4][64][8]

    const int tid  = threadIdx.x;
    const int w    = tid >> 6, lane = tid & 63;
    const int l16  = lane & 15, hi4 = lane >> 4;
    const int blk  = blockIdx.x;
    const int rg   = blk & 63, ub = blk >> 6;  // same-XCD groups (perf heuristic)
    const int bb   = rg * 64;
    const int ug   = w & 3;                    // wave's 16-unit group within block
    const int m4a  = 2 * (w >> 2);             // wave's two row-16 tiles

    // ---- LDS weights kc0-5: contiguous 96 KB from Wblob[ub] (once) ----
    {
        const unsigned short* src = Wblob + (size_t)(ub * 10) * 16 * 512;
        #pragma unroll
        for (int i = 0; i < 12; ++i) {
            int idx = (i * 512 + tid) * 8;     // 49152 shorts as 16B chunks
            *reinterpret_cast<bf16x8*>(WL + idx) =
                *reinterpret_cast<const bf16x8*>(src + idx);
        }
    }
    // ---- register weights kc6-9 (wave's ug slice): 64 VGPRs ----
    bf16x8 Breg[4][4];
    #pragma unroll
    for (int i = 0; i < 4; ++i)
        #pragma unroll
        for (int g = 0; g < 4; ++g)
            Breg[i][g] = *reinterpret_cast<const bf16x8*>(
                Wblob + ((size_t)(((ub * 10 + 6 + i) * 4 + ug) * 4 + g) * 64 + lane) * 8);

    const int uu = ub * 64 + ug * 16 + l16;    // this lane's global unit
    float bz[4];
    #pragma unroll
    for (int g = 0; g < 4; ++g) bz[g] = bias[g * 256 + uu] * LOG2E;
    const float bdv = bd[(w & 3) * 16 + l16];  // dense: ft = w&3

    float c_reg[2][4];
    #pragma unroll
    for (int m = 0; m < 2; ++m)
        #pragma unroll
        for (int j = 0; j < 4; ++j) c_reg[m][j] = 0.0f;

    const int tmax = SEQ_T + out_steps - 1;    // 95
    const size_t HB = (size_t)64 * 16384;      // parity stride (shorts)
    unsigned int* flagp = flags + rg * 32;     // group's 4 flags (128B line)

    // ---- x prefetch registers (x(0)) ----
    const int xr = tid >> 3, xc8 = (tid & 7) * 8;
    float4 xq0, xq1;
    {
        const float* xs = inputs + ((size_t)(bb + xr) * SEQ_T + 0) * FDIM + xc8;
        xq0 = *reinterpret_cast<const float4*>(xs);
        xq1 = *reinterpret_cast<const float4*>(xs + 4);
    }

    #pragma unroll 1
    for (int t = 0; ; ++t) {
        const int p = t & 1;

        // ---- stage h_t -> A kc2-9 (t=0: zeros) ----
        if (t == 0) {
            #pragma unroll
            for (int i = 0; i < 8; ++i)
                *reinterpret_cast<ull*>(A_s + 4096 + (i * 512 + tid) * 4) = 0ull;
        } else {
            const ull* src = reinterpret_cast<const ull*>(
                hbuf + p * HB + (size_t)rg * 16384);
            ull vbuf[8];
            #pragma unroll
            for (int i = 0; i < 8; ++i) vbuf[i] = agload(src + (size_t)i * 512 + tid);
            #pragma unroll
            for (int i = 0; i < 8; ++i)
                *reinterpret_cast<ull*>(A_s + 4096 + (i * 512 + tid) * 4) = vbuf[i];
        }
        if (t < SEQ_T) {
            // ---- stage x(t) from prefetch regs -> A kc0,1 ----
            bf16x8 pk = pack8(xq0, xq1);
            int kcx = xc8 >> 5;
            int lb  = (xr & 15) | ((((xc8 & 31) >> 3) & 3) << 4);
            *reinterpret_cast<bf16x8*>(A_s + ((kcx * 4 + (xr >> 4)) * 64 + lb) * 8) = pk;
            __syncthreads();                   // A ready
            if (t + 1 < SEQ_T) {               // prefetch x(t+1) under z/gates
                const float* xs = inputs + ((size_t)(bb + xr) * SEQ_T + (t + 1)) * FDIM + xc8;
                xq0 = *reinterpret_cast<const float4*>(xs);
                xq1 = *reinterpret_cast<const float4*>(xs + 4);
            }
        } else {
            __syncthreads();                   // h staged
            // ---- dense head (redundant in all 4 blocks): ft=w&3, rows m4a,m4a+1 ----
            const int s = t - SEQ_T;
            const int f = (w & 3) * 16 + l16;
            f32x4 accp[2] = {{0.f,0.f,0.f,0.f},{0.f,0.f,0.f,0.f}};
            #pragma unroll
            for (int kcd = 0; kcd < 8; ++kcd) {
                bf16x8 bw = *reinterpret_cast<const bf16x8*>(
                    Wdblob + (size_t)((((w & 3) * 8 + kcd) * 64) + lane) * 8);
                #pragma unroll
                for (int m = 0; m < 2; ++m) {
                    bf16x8 a = *reinterpret_cast<const bf16x8*>(
                        A_s + (((2 + kcd) * 4 + (m4a + m)) * 64 + lane) * 8);
                    accp[m] = __builtin_amdgcn_mfma_f32_16x16x32_bf16(a, bw, accp[m], 0, 0, 0);
                }
            }
            const int kcx = f >> 5;
            const int lsh = (((f & 31) >> 3) & 3) << 4;
            #pragma unroll
            for (int m = 0; m < 2; ++m) {
                #pragma unroll
                for (int j = 0; j < 4; ++j) {
                    int row = (m4a + m) * 16 + hi4 * 4 + j;
                    float v = accp[m][j] + bdv;
                    if (ub == 0)
                        out[((size_t)(bb + row) * out_steps + s) * FDIM + f] = v;
                    A_s[((kcx * 4 + (row >> 4)) * 64 + ((row & 15) | lsh)) * 8 + (f & 7)] = f2bf(v);
                }
            }
            if (t == tmax) break;
            __syncthreads();                   // feedback x staged
        }

        // ================ z = [x|h] @ Wslice : weights resident ================
        f32x4 acc[2][4];
        #pragma unroll
        for (int m = 0; m < 2; ++m)
            #pragma unroll
            for (int g = 0; g < 4; ++g) acc[m][g] = (f32x4){0.f, 0.f, 0.f, 0.f};

        #pragma unroll
        for (int kc = 0; kc < NKC; ++kc) {
            bf16x8 a0 = *reinterpret_cast<const bf16x8*>(
                A_s + ((kc * 4 + m4a) * 64 + lane) * 8);
            bf16x8 a1 = *reinterpret_cast<const bf16x8*>(
                A_s + ((kc * 4 + m4a + 1) * 64 + lane) * 8);
            #pragma unroll
            for (int g = 0; g < 4; ++g) {
                bf16x8 bw = (kc < 6)
                    ? *reinterpret_cast<const bf16x8*>(
                          WL + (((kc * 4 + ug) * 4 + g) * 64 + lane) * 8)
                    : Breg[kc - 6][g];
                acc[0][g] = __builtin_amdgcn_mfma_f32_16x16x32_bf16(a0, bw, acc[0][g], 0, 0, 0);
                acc[1][g] = __builtin_amdgcn_mfma_f32_16x16x32_bf16(a1, bw, acc[1][g], 0, 0, 0);
            }
        }

        // ================ gates + state -> hst (LDS) ================
        const int kcb = (w & 3) >> 1;          // unit block-half
        const int lsh2 = ((((w & 3) & 1) * 2 + (l16 >> 3)) & 3) << 4;
        #pragma unroll
        for (int m = 0; m < 2; ++m) {
            #pragma unroll
            for (int j = 0; j < 4; ++j) {
                float zi = acc[m][0][j] + bz[0];
                float zf = acc[m][1][j] + bz[1];
                float zg = acc[m][2][j] + bz[2];
                float zo = acc[m][3][j] + bz[3];
                float ig = sig2(zi);
                float fg = sig2(zf);
                float og = sig2(zo);
                float cn = fg * c_reg[m][j] + ig * tanh2(zg);
                c_reg[m][j] = cn;
                float hv = og * tanhc(cn);
                int rl = hi4 * 4 + j;
                hst[((kcb * 4 + (m4a + m)) * 64 + (rl | lsh2)) * 8 + (l16 & 7)] = f2bf(hv);
            }
        }
        __syncthreads();                       // hst complete; A reads done

        // ---- hst (8 KB) -> hbuf[1-p][rg] (agent-scope stores, land in L3) ----
        {
            ull* dst = reinterpret_cast<ull*>(
                hbuf + (1 - p) * HB + (size_t)rg * 16384 + (size_t)(2 * ub) * 2048);
            const ull* src = reinterpret_cast<const ull*>(hst);
            agstore(dst + tid,       src[tid]);
            agstore(dst + 512 + tid, src[512 + tid]);
        }

        // ---- per-group FLAG barrier (4 blocks, no RMW) ----
        __syncthreads();                       // drains vmcnt: h stores at L3
        if (tid == 0)
            __hip_atomic_store(flagp + ub, (unsigned)(t + 1),
                               __ATOMIC_RELAXED, __HIP_MEMORY_SCOPE_AGENT);
        if (tid < 4) {
            while (__hip_atomic_load(flagp + tid, __ATOMIC_RELAXED,
                                     __HIP_MEMORY_SCOPE_AGENT) < (unsigned)(t + 1))
                __builtin_amdgcn_s_sleep(1);
        }
        __syncthreads();                       // all threads released
    }
}

extern "C" void kernel_launch(void* const* d_in, const int* in_sizes, int n_in,
                              void* d_out, int out_size, void* d_ws, size_t ws_size,
                              hipStream_t stream) {
    const float* inputs = (const float*)d_in[0];
    const float* W      = (const float*)d_in[1];
    const float* U      = (const float*)d_in[2];
    const float* b      = (const float*)d_in[3];
    const float* Wd     = (const float*)d_in[4];
    const float* bd     = (const float*)d_in[5];
    float* out = (float*)d_out;

    const int out_steps = out_size / (BATCH * FDIM);   // 24

    char* ws = (char*)d_ws;
    unsigned short* Wblob  = (unsigned short*)(ws);               // 640 KB
    unsigned short* Wdblob = (unsigned short*)(ws + (1u << 20));  // 32 KB
    unsigned short* hbuf   = (unsigned short*)(ws + (2u << 20));  // 4 MB
    unsigned int*   flags  = (unsigned int*)(ws + (6u << 20));    // 64 x 128 B

    prep_wblob<<<160, 256, 0, stream>>>(W, U, Wblob);
    prep_wdblob<<<8, 256, 0, stream>>>(Wd, Wdblob);
    hipMemsetAsync(flags, 0, 64 * 128, stream);

    (void)hipFuncSetAttribute((const void*)lstm_persistent,
                              hipFuncAttributeMaxDynamicSharedMemorySize, LDS_BYTES);

    lstm_persistent<<<dim3(256), dim3(512), LDS_BYTES, stream>>>(
        inputs, b, Wblob, Wdblob, bd, hbuf, flags, out, out_steps);
}